// Round 20
// baseline (129.351 us; speedup 1.0000x reference)
//
#include <hip/hip_runtime.h>

// x: (128, 55, 55, 96) NHWC fp32; kernel: (96, 5, 5) fp32 depthwise; out = x + dwconv(x,k)
#define NB 128
#define HW 55
#define IMG (HW * HW)            // 3025
#define CH 96
#define GROUPS 24                // float4 channel-groups
#define TAPS 25
#define NPIX (NB * IMG)
#define RSTRIP 5                 // output rows per block (55 = 5*11, exact)
#define NSTRIP (HW / RSTRIP)     // 11
#define NWG (NB * NSTRIP)        // 1408 blocks
#define SROWS (RSTRIP + 4)       // 9 staged rows (halo +-2)
#define GCHUNK 4                 // active groups staged per pass
#define SLOTG 32                 // per-group slot capacity in the global table
#define NXCD 8
#define BITEMS (RSTRIP * HW * GROUPS)  // 6600 f4 items per block
#define QTR (BITEMS / 4)         // 1650
#define SPIX (RSTRIP * HW)       // 275 strip pixels per block
#define STAGEN (SROWS * HW)      // 495 staged pixels

typedef float v4f __attribute__((ext_vector_type(4)));

// ---- workspace ----
// float4 wslot[24][SLOTG]; int2 dslot[24][SLOTG] ({dh+2, dw}); int tapflag[24];
// int gact[24] (ascending); int nga, nspad, amask

__global__ void repack_kernel(const float* __restrict__ k,
                              float4* __restrict__ wslot,
                              int2* __restrict__ dslot,
                              int* __restrict__ tapflag,
                              int* __restrict__ gact,
                              int* __restrict__ nga,
                              int* __restrict__ nspad,
                              int* __restrict__ amask) {
    __shared__ int s_ns[GROUPS];
    int g = threadIdx.x;
    if (g < GROUPS) {
        int ns = 0;
        for (int tap = 0; tap < TAPS; ++tap) {
            float w0 = k[(4 * g + 0) * TAPS + tap];
            float w1 = k[(4 * g + 1) * TAPS + tap];
            float w2 = k[(4 * g + 2) * TAPS + tap];
            float w3 = k[(4 * g + 3) * TAPS + tap];
            if (w0 != 0.f || w1 != 0.f || w2 != 0.f || w3 != 0.f) {
                int dh = tap / 5 - 2, dw = tap % 5 - 2;
                wslot[g * SLOTG + ns] = make_float4(w0, w1, w2, w3);
                dslot[g * SLOTG + ns] = make_int2(dh + 2, dw);
                ++ns;
            }
        }
        for (int s = ns; s < SLOTG; ++s) {           // pads: weight 0 -> contribute 0
            wslot[g * SLOTG + s] = make_float4(0.f, 0.f, 0.f, 0.f);
            dslot[g * SLOTG + s] = make_int2(2, 0);  // center, always valid
        }
        tapflag[g] = (ns > 0) ? 1 : 0;
        s_ns[g] = ns;
    }
    __syncthreads();
    if (threadIdx.x == 0) {
        int na = 0, m = 0, msk = 0;
        for (int gg = 0; gg < GROUPS; ++gg)          // ascending order
            if (s_ns[gg] > 0) {
                gact[na++] = gg;
                msk |= (1 << gg);
                m = m > s_ns[gg] ? m : s_ns[gg];
            }
        *nga = na;
        *nspad = (m + 7) & ~7;
        *amask = msk;
    }
}

// ---- fused kernel: masked copy (no LDS dep) || stage -> 1 barrier -> conv+store ----
// LDS ~= 32.4 KB -> 4 blocks/CU; ONE barrier per block (single chunk).
__global__ __launch_bounds__(256) void tiled_kernel(const float* __restrict__ x,
                                                    const float4* __restrict__ wslot,
                                                    const int2* __restrict__ dslot,
                                                    const int* __restrict__ gact,
                                                    const int* __restrict__ p_nga,
                                                    const int* __restrict__ p_nspad,
                                                    const int* __restrict__ p_amask,
                                                    float* __restrict__ out) {
    __shared__ v4f s_x[GCHUNK * STAGEN];      // planar halo tile     31680 B
    __shared__ float4 s_w[GCHUNK * 8];        // first 8-slot batch     512 B
    __shared__ int s_d[GCHUNK * 8];           // packed (dh+2)<<8|(dw+2) 128 B
    __shared__ int s_gg[GCHUNK];              // chunk-local -> group

    // Bijective chunked XCD swizzle (1408 % 8 == 0): contiguous strips per XCD.
    const int q = NWG / NXCD, r = NWG % NXCD;
    int xcd = blockIdx.x & (NXCD - 1);
    int bidx = blockIdx.x >> 3;
    int swz = (xcd < r ? xcd * (q + 1) : r * (q + 1) + (xcd - r) * q) + bidx;

    const int n = swz / NSTRIP;
    const int strip = swz % NSTRIP;
    const int h0 = strip * RSTRIP;
    const int tid = threadIdx.x;
    const int nga = *p_nga;
    const int amask = *p_amask;               // uniform scalar
    const int nsb = (*p_nspad) >> 3;
    const int base_f4 = (n * IMG + h0 * HW) * GROUPS;
    const v4f* x4 = (const v4f*)x;
    v4f* o4 = (v4f*)out;

    // ---- phase B: masked dense copy of never-active items (no LDS dependency;
    // issues ahead of / overlapping the stage). Plain stores -> L2 merges the
    // holes with phase A's stores before writeback.
    for (int jj = tid; jj < QTR; jj += 256) {
        v4f a0 = x4[base_f4 + jj];
        v4f a1 = x4[base_f4 + jj + QTR];
        v4f a2 = x4[base_f4 + jj + 2 * QTR];
        v4f a3 = x4[base_f4 + jj + 3 * QTR];
#pragma unroll
        for (int kq = 0; kq < 4; ++kq) {
            const int i = jj + kq * QTR;
            const int gout = i % GROUPS;
            if (!((amask >> gout) & 1)) {
                v4f v = kq == 0 ? a0 : kq == 1 ? a1 : kq == 2 ? a2 : a3;
                o4[base_f4 + i] = v;
            }
        }
    }

    int nchunk = (nga + GCHUNK - 1) / GCHUNK; // 0 active -> copy above did it all
    for (int c = 0; c < nchunk; ++c) {
        const int c0 = c * GCHUNK;
        int cn = nga - c0;
        if (cn > GCHUNK) cn = GCHUNK;

        if (tid < cn) s_gg[tid] = gact[c0 + tid];
        if (tid < cn * 8) {                    // stage first slot batch
            int ci = tid >> 3, s = tid & 7;
            int gg = gact[c0 + ci];
            s_w[tid] = wslot[gg * SLOTG + s];
            int2 dd = dslot[gg * SLOTG + s];
            s_d[tid] = (dd.x << 8) | (dd.y + 2);
        }
        // stage x halo tile, 4-way MLP unrolled (independent loads issue together)
        const int stcnt = STAGEN * cn;
        const int wcn = HW * cn;
        const int sq = (stcnt + 3) >> 2;
        for (int jj = tid; jj < sq; jj += 256) {
            int idx[4];
            v4f val[4];
#pragma unroll
            for (int kq = 0; kq < 4; ++kq) {
                int i = jj + kq * sq;
                idx[kq] = -1;
                if (i < stcnt) {
                    int srow = i / wcn;
                    int rem2 = i - srow * wcn;
                    int pix = rem2 / cn;
                    int ci = rem2 - pix * cn;
                    int h = h0 - 2 + srow;
                    v4f v = {0.f, 0.f, 0.f, 0.f};
                    if ((unsigned)h < (unsigned)HW)
                        v = x4[(n * IMG + h * HW + pix) * GROUPS + gact[c0 + ci]];
                    idx[kq] = ci * STAGEN + srow * HW + pix;
                    val[kq] = v;
                }
            }
#pragma unroll
            for (int kq = 0; kq < 4; ++kq)
                if (idx[kq] >= 0) s_x[idx[kq]] = val[kq];
        }
        __syncthreads();                       // the block's ONE barrier (per chunk)

        // ---- phase A: lane-dense conv; residual from LDS; direct final store ----
        const int acnt = cn * SPIX;
        for (int j = tid; j < acnt; j += 256) {
            int ci = j / SPIX;                 // compile-time magic-mul
            int pixrel = j - ci * SPIX;
            int rr = pixrel / HW;
            int pix = pixrel - rr * HW;
            const v4f* sxg = s_x + ci * STAGEN;
            v4f acc = sxg[(rr + 2) * HW + pix];        // residual (center) from LDS
#pragma unroll
            for (int si = 0; si < 8; ++si) {
                int d = s_d[ci * 8 + si];
                int srow = rr + (d >> 8);
                int pix2 = pix + (d & 255) - 2;
                bool valid = (unsigned)pix2 < (unsigned)HW;
                float sc = valid ? 1.f : 0.f;
                int p2 = valid ? pix2 : 0;
                v4f xv = sxg[srow * HW + p2];
                float4 wv = s_w[ci * 8 + si];
                acc.x += (wv.x * sc) * xv.x;
                acc.y += (wv.y * sc) * xv.y;
                acc.z += (wv.z * sc) * xv.z;
                acc.w += (wv.w * sc) * xv.w;
            }
            for (int sb = 1; sb < nsb; ++sb) {  // rare tail (generality; none here)
                int gg = s_gg[ci];
#pragma unroll
                for (int si = 0; si < 8; ++si) {
                    int s = sb * 8 + si;
                    int2 dd = dslot[gg * SLOTG + s];
                    int srow = rr + dd.x;
                    int pix2 = pix + dd.y;
                    bool valid = (unsigned)pix2 < (unsigned)HW;
                    float sc = valid ? 1.f : 0.f;
                    int p2 = valid ? pix2 : 0;
                    v4f xv = sxg[srow * HW + p2];
                    float4 wv = wslot[gg * SLOTG + s];
                    acc.x += (wv.x * sc) * xv.x;
                    acc.y += (wv.y * sc) * xv.y;
                    acc.z += (wv.z * sc) * xv.z;
                    acc.w += (wv.w * sc) * xv.w;
                }
            }
            // final output for this active item; plain store, L2-merged
            o4[base_f4 + pixrel * GROUPS + s_gg[ci]] = acc;
        }
        if (c + 1 < nchunk) __syncthreads();   // before s_x reuse (rare)
    }
}

// ---- Fallback (ws too small): monolithic, reads raw k — correctness only ----
__global__ __launch_bounds__(256) void fallback_kernel(const float* __restrict__ x,
                                                       const float* __restrict__ kraw,
                                                       float* __restrict__ out) {
    int t = blockIdx.x * 256 + threadIdx.x;
    if (t >= NPIX * GROUPS) return;
    int g = t % GROUPS;
    int pixel = t / GROUPS;
    int rem = pixel % IMG;
    int h = rem / HW;
    int w = rem - h * HW;
    int base = pixel * CH + g * 4;
    const float4 xc = *reinterpret_cast<const float4*>(x + base);
    float4 acc = make_float4(xc.x, xc.y, xc.z, xc.w);
#pragma unroll
    for (int dh = -2; dh <= 2; ++dh)
#pragma unroll
        for (int dw = -2; dw <= 2; ++dw) {
            const int tap = (dh + 2) * 5 + (dw + 2);
            const bool valid = ((unsigned)(h + dh) < (unsigned)HW) &
                               ((unsigned)(w + dw) < (unsigned)HW);
            const float vs = valid ? 1.0f : 0.0f;
            const int off = valid ? (dh * HW * CH + dw * CH) : 0;
            const float4 xv = *reinterpret_cast<const float4*>(x + base + off);
            acc.x += (kraw[(g * 4 + 0) * TAPS + tap] * vs) * xv.x;
            acc.y += (kraw[(g * 4 + 1) * TAPS + tap] * vs) * xv.y;
            acc.z += (kraw[(g * 4 + 2) * TAPS + tap] * vs) * xv.z;
            acc.w += (kraw[(g * 4 + 3) * TAPS + tap] * vs) * xv.w;
        }
    *reinterpret_cast<float4*>(out + base) = acc;
}

extern "C" void kernel_launch(void* const* d_in, const int* in_sizes, int n_in,
                              void* d_out, int out_size, void* d_ws, size_t ws_size,
                              hipStream_t stream) {
    const float* x = (const float*)d_in[0];
    const float* k = (const float*)d_in[1];
    float* out = (float*)d_out;

    const size_t sz_wslot = (size_t)GROUPS * SLOTG * sizeof(float4);   // 12288
    const size_t sz_dslot = (size_t)GROUPS * SLOTG * sizeof(int2);     // 6144
    const size_t sz_flag = GROUPS * sizeof(int);
    const size_t sz_gact = GROUPS * sizeof(int);
    const size_t ws_need = sz_wslot + sz_dslot + sz_flag + sz_gact + 3 * sizeof(int);

    if (ws_size >= ws_need) {
        char* p = (char*)d_ws;
        float4* wslot = (float4*)p;  p += sz_wslot;
        int2* dslot = (int2*)p;      p += sz_dslot;
        int* tapflag = (int*)p;      p += sz_flag;
        int* gact = (int*)p;         p += sz_gact;
        int* nga = (int*)p;          p += sizeof(int);
        int* nspad = (int*)p;        p += sizeof(int);
        int* amask = (int*)p;

        repack_kernel<<<1, 64, 0, stream>>>(k, wslot, dslot, tapflag, gact,
                                            nga, nspad, amask);
        tiled_kernel<<<NWG, 256, 0, stream>>>(x, wslot, dslot, gact, nga, nspad,
                                              amask, out);
    } else {
        const int blocks = (NPIX * GROUPS) / 256;
        fallback_kernel<<<blocks, 256, 0, stream>>>(x, k, out);
    }
}

// Round 21
// 91.187 us; speedup vs baseline: 1.4185x; 1.4185x over previous
//
#include <hip/hip_runtime.h>

// x: (128, 55, 55, 96) NHWC fp32; kernel: (96, 5, 5) fp32 depthwise; out = x + dwconv(x,k)
#define NB 128
#define HW 55
#define IMG (HW * HW)            // 3025
#define CH 96
#define GROUPS 24                // float4 channel-groups
#define TAPS 25
#define NPIX (NB * IMG)
#define RSTRIP 5                 // output rows per block (55 = 5*11, exact)
#define NSTRIP (HW / RSTRIP)     // 11
#define NWG (NB * NSTRIP)        // 1408 blocks
#define SROWS (RSTRIP + 4)       // 9 staged rows (halo +-2)
#define PADW (HW + 4)            // 59: zero-padded columns kill w-boundary tests
#define GCHUNK 4                 // active groups staged per pass
#define SLOTG 32                 // per-group slot capacity in the global table
#define NXCD 8
#define BITEMS (RSTRIP * HW * GROUPS)  // 6600 f4 items per block
#define QTR (BITEMS / 4)         // 1650
#define SPIX (RSTRIP * HW)       // 275 strip pixels per block
#define SXSTRIDE (SROWS * PADW)  // 531 per group plane

typedef float v4f __attribute__((ext_vector_type(4)));

// f32x4 <-> packed bf16x4 (uint2), round-to-nearest-even
__device__ __forceinline__ unsigned bf16rne(float f) {
    unsigned u = __builtin_bit_cast(unsigned, f);
    return (u + 0x7FFFu + ((u >> 16) & 1u)) >> 16;
}
__device__ __forceinline__ uint2 pack4(v4f v) {
    uint2 r;
    r.x = bf16rne(v.x) | (bf16rne(v.y) << 16);
    r.y = bf16rne(v.z) | (bf16rne(v.w) << 16);
    return r;
}
__device__ __forceinline__ v4f unpack4(uint2 p) {
    v4f v;
    v.x = __builtin_bit_cast(float, p.x << 16);
    v.y = __builtin_bit_cast(float, p.x & 0xFFFF0000u);
    v.z = __builtin_bit_cast(float, p.y << 16);
    v.w = __builtin_bit_cast(float, p.y & 0xFFFF0000u);
    return v;
}

// ---- workspace ----
// float4 wslot[24][SLOTG]; int2 dslot[24][SLOTG] ({dh+2, dw}); int tapflag[24];
// int gact[24] (ascending); int nga, nspad, amask

__global__ void repack_kernel(const float* __restrict__ k,
                              float4* __restrict__ wslot,
                              int2* __restrict__ dslot,
                              int* __restrict__ tapflag,
                              int* __restrict__ gact,
                              int* __restrict__ nga,
                              int* __restrict__ nspad,
                              int* __restrict__ amask) {
    __shared__ int s_ns[GROUPS];
    int g = threadIdx.x;
    if (g < GROUPS) {
        int ns = 0;
        for (int tap = 0; tap < TAPS; ++tap) {
            float w0 = k[(4 * g + 0) * TAPS + tap];
            float w1 = k[(4 * g + 1) * TAPS + tap];
            float w2 = k[(4 * g + 2) * TAPS + tap];
            float w3 = k[(4 * g + 3) * TAPS + tap];
            if (w0 != 0.f || w1 != 0.f || w2 != 0.f || w3 != 0.f) {
                int dh = tap / 5 - 2, dw = tap % 5 - 2;
                wslot[g * SLOTG + ns] = make_float4(w0, w1, w2, w3);
                dslot[g * SLOTG + ns] = make_int2(dh + 2, dw);
                ++ns;
            }
        }
        for (int s = ns; s < SLOTG; ++s) {           // pads: weight 0 -> contribute 0
            wslot[g * SLOTG + s] = make_float4(0.f, 0.f, 0.f, 0.f);
            dslot[g * SLOTG + s] = make_int2(2, 0);  // center, always valid
        }
        tapflag[g] = (ns > 0) ? 1 : 0;
        s_ns[g] = ns;
    }
    __syncthreads();
    if (threadIdx.x == 0) {
        int na = 0, m = 0, msk = 0;
        for (int gg = 0; gg < GROUPS; ++gg)          // ascending: popc-prefix == index
            if (s_ns[gg] > 0) {
                gact[na++] = gg;
                msk |= (1 << gg);
                m = m > s_ns[gg] ? m : s_ns[gg];
            }
        *nga = na;
        *nspad = (m + 7) & ~7;
        *amask = msk;
    }
}

// ---- fused tiled kernel (R18 structure, bf16-packed LDS -> 6 blocks/CU) ----
// LDS ~= 26.4 KB. Phases: stage -> barrier -> lane-dense conv -> barrier -> stream.
__global__ __launch_bounds__(256) void tiled_kernel(const float* __restrict__ x,
                                                    const float4* __restrict__ wslot,
                                                    const int2* __restrict__ dslot,
                                                    const int* __restrict__ gact,
                                                    const int* __restrict__ p_nga,
                                                    const int* __restrict__ p_nspad,
                                                    const int* __restrict__ p_amask,
                                                    float* __restrict__ out) {
    __shared__ uint2 s_x[GCHUNK * SXSTRIDE];  // bf16x4 halo tile (padded cols) 16992 B
    __shared__ uint2 s_cv[GCHUNK * SPIX];     // bf16x4 conv deltas              8800 B
    __shared__ float4 s_w[GCHUNK * 8];        // first 8-slot batch               512 B
    __shared__ int s_d[GCHUNK * 8];           // packed (dh+2)<<8|(dw+2)          128 B
    __shared__ int s_gg[GCHUNK];              // chunk-local -> group              16 B

    // Bijective chunked XCD swizzle (1408 % 8 == 0): contiguous strips per XCD.
    const int q = NWG / NXCD, r = NWG % NXCD;
    int xcd = blockIdx.x & (NXCD - 1);
    int bidx = blockIdx.x >> 3;
    int swz = (xcd < r ? xcd * (q + 1) : r * (q + 1) + (xcd - r) * q) + bidx;

    const int n = swz / NSTRIP;
    const int strip = swz % NSTRIP;
    const int h0 = strip * RSTRIP;
    const int tid = threadIdx.x;
    const int nga = *p_nga;
    const int amask = *p_amask;               // uniform scalar
    const int nsb = (*p_nspad) >> 3;
    const int base_f4 = (n * IMG + h0 * HW) * GROUPS;
    const v4f* x4 = (const v4f*)x;
    v4f* o4 = (v4f*)out;

    int nchunk = (nga + GCHUNK - 1) / GCHUNK;
    if (nchunk < 1) nchunk = 1;               // nga==0 -> one pure-copy pass
    const bool single = (nchunk == 1);

    for (int c = 0; c < nchunk; ++c) {
        const int c0 = c * GCHUNK;
        int cn = nga - c0;
        if (cn > GCHUNK) cn = GCHUNK;
        if (cn < 0) cn = 0;

        if (tid < cn) s_gg[tid] = gact[c0 + tid];
        if (tid < cn * 8) {                    // stage first slot batch
            int ci = tid >> 3, s = tid & 7;
            int gg = gact[c0 + ci];
            s_w[tid] = wslot[gg * SLOTG + s];
            int2 dd = dslot[gg * SLOTG + s];
            s_d[tid] = (dd.x << 8) | (dd.y + 2);
        }
        // stage x halo tile (zero-padded rows AND columns), 4-way MLP unrolled;
        // values packed to bf16x4 (RNE) -> halves LDS
        const int stcnt = SROWS * PADW * cn;   // 2124 at cn=4
        const int wcn = PADW * cn;
        const int sq = (stcnt + 3) >> 2;
        for (int jj = tid; jj < sq; jj += 256) {
            int idx[4];
            v4f val[4];
#pragma unroll
            for (int kq = 0; kq < 4; ++kq) {
                int i = jj + kq * sq;
                idx[kq] = -1;
                if (i < stcnt) {
                    int srow = i / wcn;
                    int rem2 = i - srow * wcn;
                    int pp = rem2 / cn;        // padded col in [0,59)
                    int ci = rem2 - pp * cn;
                    int h = h0 - 2 + srow;
                    int w = pp - 2;
                    v4f v = {0.f, 0.f, 0.f, 0.f};
                    if (((unsigned)h < (unsigned)HW) & ((unsigned)w < (unsigned)HW))
                        v = x4[(n * IMG + h * HW + w) * GROUPS + gact[c0 + ci]];
                    idx[kq] = ci * SXSTRIDE + srow * PADW + pp;
                    val[kq] = v;
                }
            }
#pragma unroll
            for (int kq = 0; kq < 4; ++kq)
                if (idx[kq] >= 0) s_x[idx[kq]] = pack4(val[kq]);
        }
        __syncthreads();

        // ---- phase A: lane-dense conv; no boundary tests (padded borders) ----
        const int acnt = cn * SPIX;
        for (int j = tid; j < acnt; j += 256) {
            int ci = j / SPIX;
            int pixrel = j - ci * SPIX;
            int rr = pixrel / HW;
            int pix = pixrel - rr * HW;
            const uint2* sxg = s_x + ci * SXSTRIDE;
            v4f acc = {0.f, 0.f, 0.f, 0.f};
#pragma unroll
            for (int si = 0; si < 8; ++si) {
                int d = s_d[ci * 8 + si];
                int srow = rr + (d >> 8);               // in [0,8]
                int col = pix + (d & 255);              // in [0,58], always valid
                v4f xv = unpack4(sxg[srow * PADW + col]);
                float4 wv = s_w[ci * 8 + si];
                acc.x += wv.x * xv.x;
                acc.y += wv.y * xv.y;
                acc.z += wv.z * xv.z;
                acc.w += wv.w * xv.w;
            }
            for (int sb = 1; sb < nsb; ++sb) {  // rare tail (generality; none here)
                int gg = s_gg[ci];
#pragma unroll
                for (int si = 0; si < 8; ++si) {
                    int s = sb * 8 + si;
                    int2 dd = dslot[gg * SLOTG + s];
                    int srow = rr + dd.x;
                    int col = pix + 2 + dd.y;           // padded, always valid
                    v4f xv = unpack4(sxg[srow * PADW + col]);
                    float4 wv = wslot[gg * SLOTG + s];
                    acc.x += wv.x * xv.x;
                    acc.y += wv.y * xv.y;
                    acc.z += wv.z * xv.z;
                    acc.w += wv.w * xv.w;
                }
            }
            s_cv[ci * SPIX + pixrel] = pack4(acc);
        }
        __syncthreads();

        // ---- phase B: dense stream, 4 independent quarters (4 loads in flight);
        // residual is the EXACT fp32 global load; delta added from bf16 s_cv ----
        for (int jj = tid; jj < QTR; jj += 256) {
            v4f a0 = x4[base_f4 + jj];
            v4f a1 = x4[base_f4 + jj + QTR];
            v4f a2 = x4[base_f4 + jj + 2 * QTR];
            v4f a3 = x4[base_f4 + jj + 3 * QTR];
#pragma unroll
            for (int kq = 0; kq < 4; ++kq) {
                const int i = jj + kq * QTR;
                v4f acc = kq == 0 ? a0 : kq == 1 ? a1 : kq == 2 ? a2 : a3;
                int pr = i / GROUPS;
                int gout = i - pr * GROUPS;
                bool act = (amask >> gout) & 1;
                int aidx = __popc(amask & ((1u << gout) - 1));
                int local = aidx - c0;
                bool inchunk = act & (local >= 0) & (local < cn);
                if (inchunk) {
                    v4f cv = unpack4(s_cv[local * SPIX + pr]);
                    acc.x += cv.x; acc.y += cv.y; acc.z += cv.z; acc.w += cv.w;
                }
                if (single || inchunk || (c == 0 && !act))
                    __builtin_nontemporal_store(acc, &o4[base_f4 + i]);
            }
        }
        if (c + 1 < nchunk) __syncthreads();   // before s_x/s_cv reuse
    }
}

// ---- Fallback (ws too small): monolithic, reads raw k — correctness only ----
__global__ __launch_bounds__(256) void fallback_kernel(const float* __restrict__ x,
                                                       const float* __restrict__ kraw,
                                                       float* __restrict__ out) {
    int t = blockIdx.x * 256 + threadIdx.x;
    if (t >= NPIX * GROUPS) return;
    int g = t % GROUPS;
    int pixel = t / GROUPS;
    int rem = pixel % IMG;
    int h = rem / HW;
    int w = rem - h * HW;
    int base = pixel * CH + g * 4;
    const float4 xc = *reinterpret_cast<const float4*>(x + base);
    float4 acc = make_float4(xc.x, xc.y, xc.z, xc.w);
#pragma unroll
    for (int dh = -2; dh <= 2; ++dh)
#pragma unroll
        for (int dw = -2; dw <= 2; ++dw) {
            const int tap = (dh + 2) * 5 + (dw + 2);
            const bool valid = ((unsigned)(h + dh) < (unsigned)HW) &
                               ((unsigned)(w + dw) < (unsigned)HW);
            const float vs = valid ? 1.0f : 0.0f;
            const int off = valid ? (dh * HW * CH + dw * CH) : 0;
            const float4 xv = *reinterpret_cast<const float4*>(x + base + off);
            acc.x += (kraw[(g * 4 + 0) * TAPS + tap] * vs) * xv.x;
            acc.y += (kraw[(g * 4 + 1) * TAPS + tap] * vs) * xv.y;
            acc.z += (kraw[(g * 4 + 2) * TAPS + tap] * vs) * xv.z;
            acc.w += (kraw[(g * 4 + 3) * TAPS + tap] * vs) * xv.w;
        }
    *reinterpret_cast<float4*>(out + base) = acc;
}

extern "C" void kernel_launch(void* const* d_in, const int* in_sizes, int n_in,
                              void* d_out, int out_size, void* d_ws, size_t ws_size,
                              hipStream_t stream) {
    const float* x = (const float*)d_in[0];
    const float* k = (const float*)d_in[1];
    float* out = (float*)d_out;

    const size_t sz_wslot = (size_t)GROUPS * SLOTG * sizeof(float4);   // 12288
    const size_t sz_dslot = (size_t)GROUPS * SLOTG * sizeof(int2);     // 6144
    const size_t sz_flag = GROUPS * sizeof(int);
    const size_t sz_gact = GROUPS * sizeof(int);
    const size_t ws_need = sz_wslot + sz_dslot + sz_flag + sz_gact + 3 * sizeof(int);

    if (ws_size >= ws_need) {
        char* p = (char*)d_ws;
        float4* wslot = (float4*)p;  p += sz_wslot;
        int2* dslot = (int2*)p;      p += sz_dslot;
        int* tapflag = (int*)p;      p += sz_flag;
        int* gact = (int*)p;         p += sz_gact;
        int* nga = (int*)p;          p += sizeof(int);
        int* nspad = (int*)p;        p += sizeof(int);
        int* amask = (int*)p;

        repack_kernel<<<1, 64, 0, stream>>>(k, wslot, dslot, tapflag, gact,
                                            nga, nspad, amask);
        tiled_kernel<<<NWG, 256, 0, stream>>>(x, wslot, dslot, gact, nga, nspad,
                                              amask, out);
    } else {
        const int blocks = (NPIX * GROUPS) / 256;
        fallback_kernel<<<blocks, 256, 0, stream>>>(x, k, out);
    }
}

// Round 22
// 83.268 us; speedup vs baseline: 1.5534x; 1.0951x over previous
//
#include <hip/hip_runtime.h>

// x: (128, 55, 55, 96) NHWC fp32; kernel: (96, 5, 5) fp32 depthwise; out = x + dwconv(x,k)
#define NB 128
#define HW 55
#define IMG (HW * HW)            // 3025
#define CH 96
#define GROUPS 24                // float4 channel-groups
#define TAPS 25
#define NPIX (NB * IMG)
#define RSTRIP 5                 // output rows per block (55 = 5*11, exact)
#define NSTRIP (HW / RSTRIP)     // 11
#define NWG (NB * NSTRIP)        // 1408 blocks
#define SROWS (RSTRIP + 4)       // 9 staged rows (halo +-2)
#define GCHUNK 4                 // active groups staged per pass
#define SLOTG 32                 // per-group slot capacity in the global table
#define NXCD 8
#define BITEMS (RSTRIP * HW * GROUPS)  // 6600 f4 items per block
#define OCT (BITEMS / 8)         // 825: 8 dense chains per phase-B iteration
#define SPIX (RSTRIP * HW)       // 275 strip pixels per block
#define STAGEN (SROWS * HW)      // 495 staged pixels

typedef float v4f __attribute__((ext_vector_type(4)));

// ---- workspace ----
// float4 wslot[24][SLOTG]; int2 dslot[24][SLOTG] ({dh+2, dw}); int tapflag[24];
// int gact[24] (ascending); int nga, nspad, amask

__global__ void repack_kernel(const float* __restrict__ k,
                              float4* __restrict__ wslot,
                              int2* __restrict__ dslot,
                              int* __restrict__ tapflag,
                              int* __restrict__ gact,
                              int* __restrict__ nga,
                              int* __restrict__ nspad,
                              int* __restrict__ amask) {
    __shared__ int s_ns[GROUPS];
    int g = threadIdx.x;
    if (g < GROUPS) {
        int ns = 0;
        for (int tap = 0; tap < TAPS; ++tap) {
            float w0 = k[(4 * g + 0) * TAPS + tap];
            float w1 = k[(4 * g + 1) * TAPS + tap];
            float w2 = k[(4 * g + 2) * TAPS + tap];
            float w3 = k[(4 * g + 3) * TAPS + tap];
            if (w0 != 0.f || w1 != 0.f || w2 != 0.f || w3 != 0.f) {
                int dh = tap / 5 - 2, dw = tap % 5 - 2;
                wslot[g * SLOTG + ns] = make_float4(w0, w1, w2, w3);
                dslot[g * SLOTG + ns] = make_int2(dh + 2, dw);
                ++ns;
            }
        }
        for (int s = ns; s < SLOTG; ++s) {           // pads: weight 0 -> contribute 0
            wslot[g * SLOTG + s] = make_float4(0.f, 0.f, 0.f, 0.f);
            dslot[g * SLOTG + s] = make_int2(2, 0);  // center, always valid
        }
        tapflag[g] = (ns > 0) ? 1 : 0;
        s_ns[g] = ns;
    }
    __syncthreads();
    if (threadIdx.x == 0) {
        int na = 0, m = 0, msk = 0;
        for (int gg = 0; gg < GROUPS; ++gg)          // ascending: popc-prefix == index
            if (s_ns[gg] > 0) {
                gact[na++] = gg;
                msk |= (1 << gg);
                m = m > s_ns[gg] ? m : s_ns[gg];
            }
        *nga = na;
        *nspad = (m + 7) & ~7;
        *amask = msk;
    }
}

// ---- fused tiled kernel: stage -> lane-dense conv -> 8-way-MLP dense stream ----
__global__ __launch_bounds__(256) void tiled_kernel(const float* __restrict__ x,
                                                    const float4* __restrict__ wslot,
                                                    const int2* __restrict__ dslot,
                                                    const int* __restrict__ gact,
                                                    const int* __restrict__ p_nga,
                                                    const int* __restrict__ p_nspad,
                                                    const int* __restrict__ p_amask,
                                                    float* __restrict__ out) {
    __shared__ v4f s_x[GCHUNK * STAGEN];      // planar halo tile     31680 B
    __shared__ v4f s_cv[GCHUNK * SPIX];       // conv deltas          17600 B
    __shared__ float4 s_w[GCHUNK * 8];        // first 8-slot batch     512 B
    __shared__ int s_d[GCHUNK * 8];           // packed (dh+2)<<8|(dw+2) 128 B

    // Bijective chunked XCD swizzle (1408 % 8 == 0): contiguous strips per XCD.
    const int q = NWG / NXCD, r = NWG % NXCD;
    int xcd = blockIdx.x & (NXCD - 1);
    int bidx = blockIdx.x >> 3;
    int swz = (xcd < r ? xcd * (q + 1) : r * (q + 1) + (xcd - r) * q) + bidx;

    const int n = swz / NSTRIP;
    const int strip = swz % NSTRIP;
    const int h0 = strip * RSTRIP;
    const int tid = threadIdx.x;
    const int nga = *p_nga;
    const int amask = *p_amask;               // uniform scalar
    const int nsb = (*p_nspad) >> 3;
    const int base_f4 = (n * IMG + h0 * HW) * GROUPS;
    const v4f* x4 = (const v4f*)x;
    v4f* o4 = (v4f*)out;

    int nchunk = (nga + GCHUNK - 1) / GCHUNK;
    if (nchunk < 1) nchunk = 1;               // nga==0 -> one pure-copy pass
    const bool single = (nchunk == 1);

    for (int c = 0; c < nchunk; ++c) {
        const int c0 = c * GCHUNK;
        int cn = nga - c0;
        if (cn > GCHUNK) cn = GCHUNK;
        if (cn < 0) cn = 0;

        if (tid < cn * 8) {                    // stage first slot batch
            int ci = tid >> 3, s = tid & 7;
            int gg = gact[c0 + ci];
            s_w[tid] = wslot[gg * SLOTG + s];
            int2 dd = dslot[gg * SLOTG + s];
            s_d[tid] = (dd.x << 8) | (dd.y + 2);
        }
        // stage x halo tile, 4-way MLP unrolled (independent loads issue together)
        const int stcnt = STAGEN * cn;
        const int wcn = HW * cn;
        const int sq = (stcnt + 3) >> 2;
        for (int jj = tid; jj < sq; jj += 256) {
            int idx[4];
            v4f val[4];
#pragma unroll
            for (int kq = 0; kq < 4; ++kq) {
                int i = jj + kq * sq;
                idx[kq] = -1;
                if (i < stcnt) {
                    int srow = i / wcn;
                    int rem2 = i - srow * wcn;
                    int pix = rem2 / cn;
                    int ci = rem2 - pix * cn;
                    int h = h0 - 2 + srow;
                    v4f v = {0.f, 0.f, 0.f, 0.f};
                    if ((unsigned)h < (unsigned)HW)
                        v = x4[(n * IMG + h * HW + pix) * GROUPS + gact[c0 + ci]];
                    idx[kq] = ci * STAGEN + srow * HW + pix;
                    val[kq] = v;
                }
            }
#pragma unroll
            for (int kq = 0; kq < 4; ++kq)
                if (idx[kq] >= 0) s_x[idx[kq]] = val[kq];
        }
        __syncthreads();

        // ---- phase A: lane-dense conv over (chunk-group, strip-pixel) items ----
        const int acnt = cn * SPIX;
        for (int j = tid; j < acnt; j += 256) {
            int ci = j / SPIX;
            int pixrel = j - ci * SPIX;
            int rr = pixrel / HW;
            int pix = pixrel - rr * HW;
            const v4f* sxg = s_x + ci * STAGEN;
            v4f acc = {0.f, 0.f, 0.f, 0.f};
#pragma unroll
            for (int si = 0; si < 8; ++si) {
                int d = s_d[ci * 8 + si];
                int srow = rr + (d >> 8);
                int pix2 = pix + (d & 255) - 2;
                bool valid = (unsigned)pix2 < (unsigned)HW;
                float sc = valid ? 1.f : 0.f;
                int p2 = valid ? pix2 : 0;
                v4f xv = sxg[srow * HW + p2];
                float4 wv = s_w[ci * 8 + si];
                acc.x += (wv.x * sc) * xv.x;
                acc.y += (wv.y * sc) * xv.y;
                acc.z += (wv.z * sc) * xv.z;
                acc.w += (wv.w * sc) * xv.w;
            }
            for (int sb = 1; sb < nsb; ++sb) {  // rare tail (generality; none here)
                int gg = gact[c0 + ci];
#pragma unroll
                for (int si = 0; si < 8; ++si) {
                    int s = sb * 8 + si;
                    int2 dd = dslot[gg * SLOTG + s];
                    int srow = rr + dd.x;
                    int pix2 = pix + dd.y;
                    bool valid = (unsigned)pix2 < (unsigned)HW;
                    float sc = valid ? 1.f : 0.f;
                    int p2 = valid ? pix2 : 0;
                    v4f xv = sxg[srow * HW + p2];
                    float4 wv = wslot[gg * SLOTG + s];
                    acc.x += (wv.x * sc) * xv.x;
                    acc.y += (wv.y * sc) * xv.y;
                    acc.z += (wv.z * sc) * xv.z;
                    acc.w += (wv.w * sc) * xv.w;
                }
            }
            s_cv[ci * SPIX + pixrel] = acc;
        }
        __syncthreads();

        // ---- phase B: dense stream, 8 independent chains (8 loads in flight) ----
        for (int jj = tid; jj < OCT; jj += 256) {
            v4f a[8];
#pragma unroll
            for (int kq = 0; kq < 8; ++kq)       // 8 independent coalesced loads
                a[kq] = x4[base_f4 + jj + kq * OCT];
#pragma unroll
            for (int kq = 0; kq < 8; ++kq) {
                const int i = jj + kq * OCT;
                v4f acc = a[kq];
                int pr = i / GROUPS;
                int gout = i - pr * GROUPS;
                bool act = (amask >> gout) & 1;
                int aidx = __popc(amask & ((1u << gout) - 1));
                int local = aidx - c0;
                bool inchunk = act & (local >= 0) & (local < cn);
                if (inchunk) acc += s_cv[local * SPIX + pr];
                if (single || inchunk || (c == 0 && !act))
                    __builtin_nontemporal_store(acc, &o4[base_f4 + i]);
            }
        }
        if (c + 1 < nchunk) __syncthreads();   // before s_x/s_cv reuse
    }
}

// ---- Fallback (ws too small): monolithic, reads raw k — correctness only ----
__global__ __launch_bounds__(256) void fallback_kernel(const float* __restrict__ x,
                                                       const float* __restrict__ kraw,
                                                       float* __restrict__ out) {
    int t = blockIdx.x * 256 + threadIdx.x;
    if (t >= NPIX * GROUPS) return;
    int g = t % GROUPS;
    int pixel = t / GROUPS;
    int rem = pixel % IMG;
    int h = rem / HW;
    int w = rem - h * HW;
    int base = pixel * CH + g * 4;
    const float4 xc = *reinterpret_cast<const float4*>(x + base);
    float4 acc = make_float4(xc.x, xc.y, xc.z, xc.w);
#pragma unroll
    for (int dh = -2; dh <= 2; ++dh)
#pragma unroll
        for (int dw = -2; dw <= 2; ++dw) {
            const int tap = (dh + 2) * 5 + (dw + 2);
            const bool valid = ((unsigned)(h + dh) < (unsigned)HW) &
                               ((unsigned)(w + dw) < (unsigned)HW);
            const float vs = valid ? 1.0f : 0.0f;
            const int off = valid ? (dh * HW * CH + dw * CH) : 0;
            const float4 xv = *reinterpret_cast<const float4*>(x + base + off);
            acc.x += (kraw[(g * 4 + 0) * TAPS + tap] * vs) * xv.x;
            acc.y += (kraw[(g * 4 + 1) * TAPS + tap] * vs) * xv.y;
            acc.z += (kraw[(g * 4 + 2) * TAPS + tap] * vs) * xv.z;
            acc.w += (kraw[(g * 4 + 3) * TAPS + tap] * vs) * xv.w;
        }
    *reinterpret_cast<float4*>(out + base) = acc;
}

extern "C" void kernel_launch(void* const* d_in, const int* in_sizes, int n_in,
                              void* d_out, int out_size, void* d_ws, size_t ws_size,
                              hipStream_t stream) {
    const float* x = (const float*)d_in[0];
    const float* k = (const float*)d_in[1];
    float* out = (float*)d_out;

    const size_t sz_wslot = (size_t)GROUPS * SLOTG * sizeof(float4);   // 12288
    const size_t sz_dslot = (size_t)GROUPS * SLOTG * sizeof(int2);     // 6144
    const size_t sz_flag = GROUPS * sizeof(int);
    const size_t sz_gact = GROUPS * sizeof(int);
    const size_t ws_need = sz_wslot + sz_dslot + sz_flag + sz_gact + 3 * sizeof(int);

    if (ws_size >= ws_need) {
        char* p = (char*)d_ws;
        float4* wslot = (float4*)p;  p += sz_wslot;
        int2* dslot = (int2*)p;      p += sz_dslot;
        int* tapflag = (int*)p;      p += sz_flag;
        int* gact = (int*)p;         p += sz_gact;
        int* nga = (int*)p;          p += sizeof(int);
        int* nspad = (int*)p;        p += sizeof(int);
        int* amask = (int*)p;

        repack_kernel<<<1, 64, 0, stream>>>(k, wslot, dslot, tapflag, gact,
                                            nga, nspad, amask);
        tiled_kernel<<<NWG, 256, 0, stream>>>(x, wslot, dslot, gact, nga, nspad,
                                              amask, out);
    } else {
        const int blocks = (NPIX * GROUPS) / 256;
        fallback_kernel<<<blocks, 256, 0, stream>>>(x, k, out);
    }
}